// Round 3
// baseline (104.604 us; speedup 1.0000x reference)
//
#include <hip/hip_runtime.h>

// out[n, mu, mup] = sum_{m1+m2==mu+4} sum_{m1p+m2p==mup+4}
//     C[m1,m2]*C[m1p,m2p] * X1[n,m1,m1p] * X2[n,m2,m2p]
//
// R18: persistent double-buffered pipeline around the R15-verbatim compute.
//  - R16/R17 post-mortem: cutting VALU 25% + coalescing stores = NEUTRAL
//    -> kernel is NOT compute-throughput-bound. Bottleneck is the serial
//    stage -> vmcnt(0)-drain -> compute structure (per-tile ~10k cyc vs
//    max(mem 6.1k, compute 4k) if overlapped).
//  - Grid = 256 persistent blocks (1/CU; LDS 83KB), each strides tiles.
//    Per iteration: __syncthreads (drains DMA of THIS tile, issued last
//    iteration) -> issue async DMA for tile+256 into the other buffer ->
//    compute this tile -> store. Prefetch has the whole compute phase
//    (~1.7us >> HBM latency) to land, so the drain is ~free.
//  - Hazards: write-after-read on buffers is ordered by the same single
//    __syncthreads per iteration (all waves finish reading buf before any
//    wave issues the next DMA into it, 2 iterations later).
//  - Compute/store: R15-verbatim (9 waves, wave = mu, lane = n-local;
//    stride-81 LDS reads = 2 lanes/bank = conflict-free).
// HARD RULES kept: w0[61] inline SGPR, const-indexed only; no
// runtime-indexed register arrays; launch is graph-capture-safe.

namespace {

struct QTab {
  int m1p[61];
  int m2p[61];
  int mup[61];
  constexpr QTab() : m1p{}, m2p{}, mup{} {
    int idx = 0;
    for (int mu = 0; mu < 9; ++mu)
      for (int a = 0; a < 9; ++a) {
        int b = mu + 4 - a;
        if (b >= 0 && b < 9) {
          m1p[idx] = a; m2p[idx] = b; mup[idx] = mu; ++idx;
        }
      }
  }
};
constexpr QTab QT{};

}  // namespace

// pairs per mu: [5,6,7,8,9,8,7,6,5]; prefix = first pair index of each mu
__constant__ __device__ int kPrefix[9] = {0, 5, 11, 18, 26, 35, 43, 50, 56};

__device__ __forceinline__ float uniform_f32(float v) {
  return __int_as_float(__builtin_amdgcn_readfirstlane(__float_as_int(v)));
}

typedef unsigned int u32;

// Async global->LDS DMA. Per-lane global src; LDS dest = uniform base +
// lane*SZ. Counts in vmcnt; drained by __syncthreads.
__device__ __forceinline__ void glds16(const float* g, float* lds) {
  __builtin_amdgcn_global_load_lds(
      (const __attribute__((address_space(1))) u32*)g,
      (__attribute__((address_space(3))) u32*)(u32)(uintptr_t)lds, 16, 0, 0);
}
__device__ __forceinline__ void glds4(const float* g, float* lds) {
  __builtin_amdgcn_global_load_lds(
      (const __attribute__((address_space(1))) u32*)g,
      (__attribute__((address_space(3))) u32*)(u32)(uintptr_t)lds, 4, 0, 0);
}

#define NB 64            // n per tile
#define NT 576           // threads = 9 waves (wave = mu, lane = n-local)
#define AD (NB * 81)     // 5184 dwords per array per tile
#define CH 256           // dwords per x16 wave-chunk (64 lanes * 4 dw)
#define NCH 20           // full x16 chunks per array (20*256 = 5120)
#define TAILB 5120       // tail base (64 dwords, staged at width 4)
#define GRID 256         // persistent blocks: 1 per CU (LDS-capped)

__global__ __launch_bounds__(NT)
void wigner_combine_kernel(const float* __restrict__ X1,
                           const float* __restrict__ X2,
                           const float* __restrict__ mult,
                           float* __restrict__ out, int N) {
  __shared__ __align__(16) float x1s[2][AD];  // 2 x 20736 B, linear [n][81]
  __shared__ __align__(16) float x2s[2][AD];  // 2 x 20736 B
  __shared__ float csh[61];                   // per-pair scales c_p/c_0

  const int t = threadIdx.x;
  const int w = t >> 6;      // wave id 0..8
  const int lane = t & 63;
  const long totaldw = (long)N * 81;
  const int ntiles = (N + NB - 1) / NB;

  // ---- weight row 0 -> 61 SGPRs (inline, constant indices ONLY) ----
  float w0[61];
#pragma unroll
  for (int q = 0; q < 61; ++q) w0[q] = uniform_f32(mult[q]);

  if (t < 61) csh[t] = mult[t] * (1.0f / mult[0]);

  // stage tile tt into buffer b: async linear DMA, both arrays.
  // 40 x16 chunks + 2 x4 tails distributed over 9 waves (R15-verbatim).
  auto stage = [&](int tt, int b) {
    const long gb = (long)tt * AD;
#pragma unroll
    for (int k = 0; k < 5; ++k) {
      const int i = w + 9 * k;  // wave-uniform chunk id
      if (i < 2 * NCH) {
        const int cbase = (i < NCH ? i : i - NCH) * CH;
        const float* gsrc = (i < NCH ? X1 : X2) + gb + cbase + lane * 4;
        float* ldst = (i < NCH ? x1s[b] : x2s[b]) + cbase;
        if (gb + cbase + lane * 4 < totaldw) glds16(gsrc, ldst);
      }
    }
    if (w == 0) {
      if (gb + TAILB + lane < totaldw)
        glds4(X1 + gb + TAILB + lane, x1s[b] + TAILB);
    } else if (w == 1) {
      if (gb + TAILB + lane < totaldw)
        glds4(X2 + gb + TAILB + lane, x2s[b] + TAILB);
    }
  };

  // ---- prologue: issue DMA for this block's first tile ----
  int tile = blockIdx.x;
  int buf = 0;
  if (tile < ntiles) stage(tile, 0);

  // wave-uniform mu constants (R15-verbatim)
  const int mu = __builtin_amdgcn_readfirstlane(w);
  const int m1lo = (mu - 4 > 0) ? mu - 4 : 0;
  const int pbase = kPrefix[mu];

  // ---- persistent pipeline: one __syncthreads per tile ----
  for (; tile < ntiles; tile += GRID) {
    __syncthreads();  // vmcnt(0): DMA(tile -> buf) landed; prev buf released

    const int next = tile + GRID;
    if (next < ntiles) stage(next, buf ^ 1);  // prefetch under compute

    const float* __restrict__ lx1 = x1s[buf] + lane * 81;
    const float* __restrict__ lx2 = x2s[buf] + lane * 81;

    float acc[9];
#pragma unroll
    for (int j = 0; j < 9; ++j) acc[j] = 0.0f;

#pragma unroll
    for (int m1 = 0; m1 < 9; ++m1) {
      const int m2 = mu + 4 - m1;      // wave-uniform scalar
      if (m2 < 0 || m2 > 8) continue;  // uniform guard (scalar branch)
      const int p = pbase + (m1 - m1lo);
      const float sp = csh[p];         // uniform ds_read broadcast

      float x1w[9], x2r[9];
#pragma unroll
      for (int j = 0; j < 9; ++j) x1w[j] = lx1[m1 * 9 + j] * sp;
#pragma unroll
      for (int j = 0; j < 9; ++j) x2r[j] = lx2[m2 * 9 + j];

#pragma unroll
      for (int q = 0; q < 61; ++q) {
        // weight = sp * w0[q] = c_p * c_q; w0 const-indexed (SGPRs)
        acc[QT.mup[q]] = fmaf(w0[q], x1w[QT.m1p[q]] * x2r[QT.m2p[q]],
                              acc[QT.mup[q]]);
      }
    }

    // direct stores: out[n, mu, 0..8] (block's 9 waves cover all 81
    // components of each n -> L2 merges to full lines)
    const long n = (long)tile * NB + lane;
    if (n < N) {
      float* __restrict__ op = out + n * 81 + mu * 9;
#pragma unroll
      for (int j = 0; j < 9; ++j) op[j] = acc[j];
    }

    buf ^= 1;
  }
}

extern "C" void kernel_launch(void* const* d_in, const int* in_sizes, int n_in,
                              void* d_out, int out_size, void* d_ws, size_t ws_size,
                              hipStream_t stream) {
  const float* X1 = (const float*)d_in[0];
  const float* X2 = (const float*)d_in[1];
  const float* mult = (const float*)d_in[6];
  float* out = (float*)d_out;

  const int N = in_sizes[0] / 81;
  const int ntiles = (N + NB - 1) / NB;
  const int blocks = (ntiles < GRID) ? ntiles : GRID;
  wigner_combine_kernel<<<blocks, NT, 0, stream>>>(X1, X2, mult, out, N);
}